// Round 2
// baseline (628.572 us; speedup 1.0000x reference)
//
#include <hip/hip_runtime.h>
#include <hip/hip_bf16.h>
#include <math.h>

#define NUMC 10000
#define DIMS 128
#define SZM  50
#define FD   512
#define NB   64
#define NL   200
#define NTOK (NB*NL)
#define TPB  16     // tokens per block (prep / fp kernels)
#define NG   2      // m-groups in scan
#define MG   25     // m's per group

// ws layout (float offsets)
#define OFF_K  ((size_t)0)
#define OFF_W  (OFF_K + (size_t)NTOK*DIMS)          // [NTOK][64], plain m-major (0..49), padded to 64
#define OFF_E  (OFF_W + (size_t)NTOK*64)
#define OFF_A  (OFF_E + (size_t)NTOK*DIMS)
#define OFF_PR (OFF_A + (size_t)NTOK*DIMS)          // [NG][NTOK][DIMS]

__device__ __forceinline__ float sigmoidf_(float x){ return 1.0f/(1.0f+expf(-x)); }

__global__ __launch_bounds__(256,4) void prep_kernel(
    const int* __restrict__ q, const int* __restrict__ r,
    const float* __restrict__ k_emb, const float* __restrict__ v_emb,
    const float* __restrict__ W1, const float* __restrict__ b1,
    const float* __restrict__ W2, const float* __restrict__ b2,
    const float* __restrict__ Mk,
    const float* __restrict__ We, const float* __restrict__ be,
    const float* __restrict__ Wa, const float* __restrict__ ba,
    float* __restrict__ ws)
{
    __shared__ float sk[TPB][DIMS+4];
    __shared__ float sv[TPB][DIMS+4];

    const int tid  = threadIdx.x;
    const int d    = tid & 127;
    const int half = tid >> 7;          // 0 or 1: which 8 tokens this thread handles
    const int base = blockIdx.x * TPB;
    const int t0   = half * 8;

    // wave-uniform embedding row pointers (same for all lanes in the half)
    const float* kr[8];
    const float* vr[8];
    #pragma unroll
    for (int t=0;t<8;t++){
        int tok = base + t0 + t;
        int qq  = q[tok];
        int xx  = qq + NUMC * r[tok];
        kr[t] = k_emb + (size_t)qq * FD;
        vr[t] = v_emb + (size_t)xx * FD;
    }

    float kacc[8], vacc[8];
    {
        float bb1=b1[d], bb2=b2[d];
        #pragma unroll
        for (int t=0;t<8;t++){ kacc[t]=bb1; vacc[t]=bb2; }
    }

    // k = emb_k @ W1,  v = emb_v @ W2   (K=512)
    for (int i=0;i<FD;i+=4){
        float w10=W1[(i+0)*DIMS+d], w11=W1[(i+1)*DIMS+d], w12=W1[(i+2)*DIMS+d], w13=W1[(i+3)*DIMS+d];
        float w20=W2[(i+0)*DIMS+d], w21=W2[(i+1)*DIMS+d], w22=W2[(i+2)*DIMS+d], w23=W2[(i+3)*DIMS+d];
        #pragma unroll
        for (int t=0;t<8;t++){
            float4 ek = *(const float4*)(kr[t]+i);
            float4 ev = *(const float4*)(vr[t]+i);
            kacc[t]=fmaf(ek.x,w10,fmaf(ek.y,w11,fmaf(ek.z,w12,fmaf(ek.w,w13,kacc[t]))));
            vacc[t]=fmaf(ev.x,w20,fmaf(ev.y,w21,fmaf(ev.z,w22,fmaf(ev.w,w23,vacc[t]))));
        }
    }
    #pragma unroll
    for (int t=0;t<8;t++){
        sk[t0+t][d]=kacc[t];
        sv[t0+t][d]=vacc[t];
        ws[OFF_K + (size_t)(base+t0+t)*DIMS + d] = kacc[t];
    }
    __syncthreads();

    // softmax(k @ Mk^T): 16 lanes per token, 4 m's per lane
    {
        const int t  = tid >> 4;         // token 0..15
        const int ml = tid & 15;
        float lg[4];
        #pragma unroll
        for (int j=0;j<4;j++){
            int m = ml + j*16;
            float s = -1e30f;
            if (m < SZM){
                s = 0.f;
                const float* mk = Mk + (size_t)m*DIMS;
                for (int i=0;i<DIMS;i+=4){
                    float4 kk = *(const float4*)&sk[t][i];
                    float4 m4 = *(const float4*)(mk+i);
                    s += kk.x*m4.x + kk.y*m4.y + kk.z*m4.z + kk.w*m4.w;
                }
            }
            lg[j]=s;
        }
        float mx = fmaxf(fmaxf(lg[0],lg[1]),fmaxf(lg[2],lg[3]));
        #pragma unroll
        for (int o=1;o<16;o<<=1) mx = fmaxf(mx, __shfl_xor(mx,o));
        float ex[4]; float sm=0.f;
        #pragma unroll
        for (int j=0;j<4;j++){
            int m = ml + j*16;
            ex[j] = (m<SZM) ? expf(lg[j]-mx) : 0.f;
            sm += ex[j];
        }
        #pragma unroll
        for (int o=1;o<16;o<<=1) sm += __shfl_xor(sm,o);
        float inv = 1.f/sm;
        #pragma unroll
        for (int j=0;j<4;j++){
            int m = ml + j*16;
            if (m<SZM) ws[OFF_W + (size_t)(base+t)*64 + m] = ex[j]*inv;
        }
    }

    // e = sigmoid(v@We+be), a = tanh(v@Wa+ba)   (K=128)
    float eacc[8], aacc[8];
    {
        float bbe=be[d], bba=ba[d];
        #pragma unroll
        for (int t=0;t<8;t++){ eacc[t]=bbe; aacc[t]=bba; }
    }
    for (int i=0;i<DIMS;i+=4){
        float e0=We[(i+0)*DIMS+d], e1=We[(i+1)*DIMS+d], e2=We[(i+2)*DIMS+d], e3=We[(i+3)*DIMS+d];
        float a0=Wa[(i+0)*DIMS+d], a1=Wa[(i+1)*DIMS+d], a2=Wa[(i+2)*DIMS+d], a3=Wa[(i+3)*DIMS+d];
        #pragma unroll
        for (int t=0;t<8;t++){
            float4 v4 = *(const float4*)&sv[t0+t][i];
            eacc[t]=fmaf(v4.x,e0,fmaf(v4.y,e1,fmaf(v4.z,e2,fmaf(v4.w,e3,eacc[t]))));
            aacc[t]=fmaf(v4.x,a0,fmaf(v4.y,a1,fmaf(v4.z,a2,fmaf(v4.w,a3,aacc[t]))));
        }
    }
    #pragma unroll
    for (int t=0;t<8;t++){
        size_t o=(size_t)(base+t0+t)*DIMS+d;
        ws[OFF_E+o]=sigmoidf_(eacc[t]);
        ws[OFF_A+o]=tanhf(aacc[t]);
    }
}

__global__ __launch_bounds__(128) void scan_kernel(const float* __restrict__ Mv0, float* __restrict__ ws)
{
    const int b = blockIdx.x;
    const int g = blockIdx.y;
    const int d = threadIdx.x;

    const float* wb = ws + OFF_W + (size_t)b*NL*64 + g*MG;
    const float* eb = ws + OFF_E + (size_t)b*NL*DIMS + d;
    const float* ab = ws + OFF_A + (size_t)b*NL*DIMS + d;
    float* pr = ws + OFF_PR + ((size_t)g*NTOK + (size_t)b*NL)*DIMS + d;

    float Mv[MG];
    #pragma unroll
    for (int m=0;m<MG;m++) Mv[m] = Mv0[(g*MG+m)*DIMS + d];

    float wA[MG], wB[MG];
    float eA,aA,eB,aB;
    #pragma unroll
    for (int m=0;m<MG;m++) wA[m]=wb[m];
    eA=eb[0]; aA=ab[0];

    for (int t=0;t<NL;t+=2){
        #pragma unroll
        for (int m=0;m<MG;m++) wB[m]=wb[(size_t)(t+1)*64+m];
        eB=eb[(size_t)(t+1)*DIMS]; aB=ab[(size_t)(t+1)*DIMS];

        float rt=0.f;
        #pragma unroll
        for (int m=0;m<MG;m++){
            float c=wA[m];
            rt=fmaf(c,Mv[m],rt);
            float t1=c*eA, t2=c*aA;
            Mv[m]=Mv[m]+fmaf(-t1,Mv[m],t2);
        }
        pr[(size_t)t*DIMS]=rt;

        if (t+2<NL){
            #pragma unroll
            for (int m=0;m<MG;m++) wA[m]=wb[(size_t)(t+2)*64+m];
            eA=eb[(size_t)(t+2)*DIMS]; aA=ab[(size_t)(t+2)*DIMS];
        }

        rt=0.f;
        #pragma unroll
        for (int m=0;m<MG;m++){
            float c=wB[m];
            rt=fmaf(c,Mv[m],rt);
            float t1=c*eB, t2=c*aB;
            Mv[m]=Mv[m]+fmaf(-t1,Mv[m],t2);
        }
        pr[(size_t)(t+1)*DIMS]=rt;
    }
}

__global__ __launch_bounds__(256,4) void fp_kernel(
    const float* __restrict__ ws,
    const float* __restrict__ Wf, const float* __restrict__ bf,
    const float* __restrict__ Wp, const float* __restrict__ bp,
    float* __restrict__ out)
{
    __shared__ float sr [TPB][DIMS+4];
    __shared__ float skk[TPB][DIMS+4];
    __shared__ float pf [TPB][DIMS+4];
    const int tid  = threadIdx.x;
    const int d    = tid & 127;
    const int half = tid >> 7;
    const int base = blockIdx.x*TPB;
    const int t0   = half*8;

    #pragma unroll
    for (int t=0;t<8;t++){
        size_t tok=(size_t)base+t0+t;
        sr [t0+t][d]= ws[OFF_PR + tok*DIMS + d] + ws[OFF_PR + ((size_t)NTOK+tok)*DIMS + d];
        skk[t0+t][d]= ws[OFF_K + tok*DIMS + d];
    }
    __syncthreads();

    float facc[8];
    {
        float bfj=bf[d];
        #pragma unroll
        for (int t=0;t<8;t++) facc[t]=bfj;
    }
    for (int i=0;i<DIMS;i+=4){
        float wt0=Wf[(i+0)*DIMS+d],wt1=Wf[(i+1)*DIMS+d],wt2=Wf[(i+2)*DIMS+d],wt3=Wf[(i+3)*DIMS+d];
        float wb0=Wf[(DIMS+i+0)*DIMS+d],wb1=Wf[(DIMS+i+1)*DIMS+d],wb2=Wf[(DIMS+i+2)*DIMS+d],wb3=Wf[(DIMS+i+3)*DIMS+d];
        #pragma unroll
        for (int t=0;t<8;t++){
            float4 r4=*(const float4*)&sr [t0+t][i];
            float4 k4=*(const float4*)&skk[t0+t][i];
            facc[t]=fmaf(r4.x,wt0,fmaf(r4.y,wt1,fmaf(r4.z,wt2,fmaf(r4.w,wt3,facc[t]))));
            facc[t]=fmaf(k4.x,wb0,fmaf(k4.y,wb1,fmaf(k4.z,wb2,fmaf(k4.w,wb3,facc[t]))));
        }
    }
    {
        float wpj=Wp[d];
        #pragma unroll
        for (int t=0;t<8;t++) pf[t0+t][d]=tanhf(facc[t])*wpj;
    }
    __syncthreads();
    if (tid<TPB){
        float s=bp[0];
        for (int jj=0;jj<DIMS;jj++) s+=pf[tid][jj];
        out[base+tid]=sigmoidf_(s);
    }
}

extern "C" void kernel_launch(void* const* d_in, const int* in_sizes, int n_in,
                              void* d_out, int out_size, void* d_ws, size_t ws_size,
                              hipStream_t stream)
{
    const int*   q     = (const int*)  d_in[0];
    const int*   r     = (const int*)  d_in[1];
    /* d_in[2] = diff (unused) */
    const float* k_emb = (const float*)d_in[3];
    const float* v_emb = (const float*)d_in[4];
    const float* W1    = (const float*)d_in[5];
    const float* b1    = (const float*)d_in[6];
    const float* W2    = (const float*)d_in[7];
    const float* b2    = (const float*)d_in[8];
    const float* Mk    = (const float*)d_in[9];
    const float* Mv0   = (const float*)d_in[10];
    const float* We    = (const float*)d_in[11];
    const float* be    = (const float*)d_in[12];
    const float* Wa    = (const float*)d_in[13];
    const float* ba    = (const float*)d_in[14];
    const float* Wf    = (const float*)d_in[15];
    const float* bf    = (const float*)d_in[16];
    const float* Wp    = (const float*)d_in[17];
    const float* bp    = (const float*)d_in[18];

    float* ws  = (float*)d_ws;
    float* out = (float*)d_out;

    prep_kernel<<<NTOK/TPB, 256, 0, stream>>>(q,r,k_emb,v_emb,W1,b1,W2,b2,Mk,We,be,Wa,ba,ws);
    scan_kernel<<<dim3(NB,NG), 128, 0, stream>>>(Mv0, ws);
    fp_kernel<<<NTOK/TPB, 256, 0, stream>>>(ws, Wf, bf, Wp, bp, out);
}